// Round 2
// baseline (336.220 us; speedup 1.0000x reference)
//
#include <hip/hip_runtime.h>
#include <math.h>

#define NIMG 16
#define NC   80
#define HH   200
#define WW   152
#define HWSZ (HH*WW)          // 30400
#define HW4  (HWSZ/4)         // 7600
#define KTOP 100
#define NBINS 4096
#define CAP   16384           // per-image collected candidate capacity
#define FCAP  1024            // per-block staging / finalist capacity
#define CHUNKS4 30            // ceil(7600/256)
#define CHUNKS 119            // ceil(30400/256) (fallback kernel)

// ws layout (bytes):
//   hist [16][4096] int      @ 0        (262144 B)
//   cnt  [16] int            @ 262144   (64 B)
//   Tbin [16] int            @ 262208   (64 B)
//   cand_idx [16][CAP] int   @ 262272   (1 MiB)
//   cand_val [16][CAP] float @ 1310848  (1 MiB)
#define HIST_OFF 0
#define CNT_OFF  262144
#define TBIN_OFF 262208
#define CIDX_OFF 262272
#define CVAL_OFF 1310848
#define ZERO_BYTES 262272

__device__ __forceinline__ float sigf(float x){ return 1.f/(1.f+expf(-x)); }

// Pass 1: histogram candidates with comb>0.25, collect comb>0.5 candidates.
__global__ void __launch_bounds__(256) k_hist_collect(
    const float* __restrict__ cls, const float* __restrict__ cent,
    int* __restrict__ hist, int* __restrict__ cnt,
    int* __restrict__ cand_idx, float* __restrict__ cand_val)
{
  __shared__ int lhist[NBINS];
  __shared__ int lcnt, gbase;
  __shared__ int   lidx[FCAP];
  __shared__ float lval[FCAP];
  const int n    = blockIdx.y;
  const int idx4 = blockIdx.x*256 + threadIdx.x;
  for (int b = threadIdx.x; b < NBINS; b += 256) lhist[b] = 0;
  if (threadIdx.x == 0) lcnt = 0;
  __syncthreads();
  if (idx4 < HW4) {
    const float4 ct4 = ((const float4*)cent)[n*HW4 + idx4];
    float cs[4];
    cs[0] = sigf(ct4.x); cs[1] = sigf(ct4.y); cs[2] = sigf(ct4.z); cs[3] = sigf(ct4.w);
    const float4* cp = (const float4*)(cls + (size_t)n*NC*HWSZ) + idx4;
    const int hw0 = idx4*4;
    for (int c = 0; c < NC; ++c) {
      float4 v = cp[(size_t)c*HW4];
      float x[4] = {v.x, v.y, v.z, v.w};
      #pragma unroll
      for (int e = 0; e < 4; ++e) {
        if (x[e] > -1.3867f) {            // sigmoid precheck (loose)
          float s = sigf(x[e]);
          if (s > 0.2f) {                 // exact reference condition
            float comb = s*cs[e];
            if (comb > 0.25f) {           // bins <1024 can't hold the cutoff
              int b = (int)(comb*4096.f); if (b > 4095) b = 4095;
              atomicAdd(&lhist[b], 1);
              if (comb > 0.5f) {
                int p = atomicAdd(&lcnt, 1);
                if (p < FCAP) { lidx[p] = (hw0+e)*NC + c; lval[p] = comb; }
                else {          // staging overflow (never in practice)
                  int g = atomicAdd(&cnt[n], 1);
                  if (g < CAP) { cand_idx[n*CAP+g] = (hw0+e)*NC + c; cand_val[n*CAP+g] = comb; }
                }
              }
            }
          }
        }
      }
    }
  }
  __syncthreads();
  int nc = lcnt; if (nc > FCAP) nc = FCAP;
  if (threadIdx.x == 0) gbase = atomicAdd(&cnt[n], nc);
  __syncthreads();
  for (int i = threadIdx.x; i < nc; i += 256) {
    int g = gbase + i;
    if (g < CAP) { cand_idx[n*CAP+g] = lidx[i]; cand_val[n*CAP+g] = lval[i]; }
  }
  for (int b = threadIdx.x; b < NBINS; b += 256) {
    int v = lhist[b];
    if (v) atomicAdd(&hist[n*NBINS + b], v);
  }
}

// Pass 2: per-image threshold bin T = max b with suffix_count(b) >= KTOP.
__global__ void __launch_bounds__(256) k_thresh(
    const int* __restrict__ hist, int* __restrict__ tbin)
{
  __shared__ int lh[NBINS];
  __shared__ int csum[256];
  const int n = blockIdx.x, t = threadIdx.x;
  for (int b = t; b < NBINS; b += 256) lh[b] = hist[n*NBINS + b];
  __syncthreads();
  int s = 0;
  for (int b = t*16; b < t*16+16; ++b) s += lh[b];
  csum[t] = s;
  __syncthreads();
  if (t == 0) { int run = 0; for (int i = 255; i >= 0; --i) { int tmp = csum[i]; csum[i] = run; run += tmp; } }
  __syncthreads();
  int run = csum[t];  // count of bins strictly above this chunk
  for (int b = t*16+15; b >= t*16; --b) {
    run += lh[b];                      // run = suffix(b)
    if (run >= KTOP && (run - lh[b]) < KTOP) tbin[n] = b;  // unique crossing
  }
}

// Pass 3 (safety net, early-exits for this data): collect bins [T, bin(0.5)).
__global__ void __launch_bounds__(256) k_collect_fb(
    const float* __restrict__ cls, const float* __restrict__ cent,
    const int* __restrict__ tbin, int* __restrict__ cnt,
    int* __restrict__ cand_idx, float* __restrict__ cand_val)
{
  const int n = blockIdx.y;
  const int T = tbin[n];
  if (T >= 2048) return;   // all needed candidates already collected (comb>0.5)
  __shared__ int lcnt, gbase;
  __shared__ int   lidx[FCAP];
  __shared__ float lval[FCAP];
  if (threadIdx.x == 0) lcnt = 0;
  __syncthreads();
  const int hw = blockIdx.x*256 + threadIdx.x;
  if (hw < HWSZ) {
    float csv = sigf(cent[n*HWSZ + hw]);
    const float* cp = cls + (size_t)n*NC*HWSZ + hw;
    for (int c = 0; c < NC; ++c) {
      float s = sigf(cp[(size_t)c*HWSZ]);
      if (s > 0.2f) {
        float comb = s*csv;
        if (!(comb > 0.5f)) {
          int b = (int)(comb*4096.f); if (b > 4095) b = 4095;
          if (b >= T) {
            int p = atomicAdd(&lcnt, 1);
            if (p < FCAP) { lidx[p] = hw*NC + c; lval[p] = comb; }
            else { int g = atomicAdd(&cnt[n], 1);
                   if (g < CAP) { cand_idx[n*CAP+g] = hw*NC + c; cand_val[n*CAP+g] = comb; } }
          }
        }
      }
    }
  }
  __syncthreads();
  int ncl = lcnt; if (ncl > FCAP) ncl = FCAP;
  if (threadIdx.x == 0) gbase = atomicAdd(&cnt[n], ncl);
  __syncthreads();
  for (int i = threadIdx.x; i < ncl; i += 256) {
    int g = gbase + i;
    if (g < CAP) { cand_idx[n*CAP+g] = lidx[i]; cand_val[n*CAP+g] = lval[i]; }
  }
}

// Pass 4: per image — exact top-100 (f64 rank), decode, NMS, write outputs.
__global__ void __launch_bounds__(256) k_final(
    const float* __restrict__ cls, const float* __restrict__ cent,
    const float* __restrict__ reg, const float* __restrict__ locs,
    const int* __restrict__ tbin, const int* __restrict__ cnt,
    const int* __restrict__ cand_idx, const float* __restrict__ cand_val,
    float* __restrict__ out)
{
  const int n = blockIdx.x, tid = threadIdx.x;
  __shared__ int    fidx[FCAP];
  __shared__ double fval[FCAP];
  __shared__ int fcnt;
  __shared__ int    topidx[KTOP];
  __shared__ double topval[KTOP];
  __shared__ float bx1[KTOP], by1[KTOP], bx2[KTOP], by2[KTOP], barea[KTOP];
  __shared__ float ox1[KTOP], oy1[KTOP], ox2[KTOP], oy2[KTOP], osc[KTOP];
  __shared__ int olab[KTOP];
  __shared__ unsigned char oval[KTOP], okeep[KTOP];
  if (tid == 0) fcnt = 0;
  for (int k = tid; k < KTOP; k += 256) topidx[k] = -1;
  __syncthreads();
  const int T = tbin[n];
  int m = cnt[n]; if (m > CAP) m = CAP;
  for (int i = tid; i < m; i += 256) {
    float v = cand_val[n*CAP + i];
    int b = (int)(v*4096.f); if (b > 4095) b = 4095;
    if (b >= T) { int p = atomicAdd(&fcnt, 1); if (p < FCAP) fidx[p] = cand_idx[n*CAP + i]; }
  }
  __syncthreads();
  int mf = fcnt; if (mf > FCAP) mf = FCAP;
  // f64 recompute of combined score for robust ordering
  for (int i = tid; i < mf; i += 256) {
    int idx = fidx[i]; int loc = idx / NC; int c = idx - loc*NC;
    double s  = 1.0/(1.0 + exp(-(double)cls[(size_t)n*NC*HWSZ + (size_t)c*HWSZ + loc]));
    double ct = 1.0/(1.0 + exp(-(double)cent[n*HWSZ + loc]));
    fval[i] = s*ct;
  }
  __syncthreads();
  // exact rank (desc value, asc index tie-break)
  for (int i = tid; i < mf; i += 256) {
    double vi = fval[i]; int ii = fidx[i]; int r = 0;
    for (int j = 0; j < mf; ++j) {
      double vj = fval[j];
      r += (vj > vi) || (vj == vi && fidx[j] < ii);
    }
    if (r < KTOP) { topidx[r] = ii; topval[r] = vi; }
  }
  __syncthreads();
  if (tid < KTOP) {
    int idx = topidx[tid];
    float x1, y1, x2, y2, sc; int lab; bool vld;
    if (idx >= 0) {
      int loc = idx / NC; int c = idx - loc*NC; lab = c + 1;
      float lx = locs[2*loc], ly = locs[2*loc + 1];
      const float* rp = reg + (size_t)n*4*HWSZ;
      float dl = rp[loc], dt = rp[HWSZ + loc], dr = rp[2*HWSZ + loc], db = rp[3*HWSZ + loc];
      const float wmax = (float)(WW*8 - 1);   // 1215
      const float hmax = (float)(HH*8 - 1);   // 1599
      x1 = fminf(fmaxf(lx - dl, 0.f), wmax);
      x2 = fminf(fmaxf(lx + dr, 0.f), wmax);
      y1 = fminf(fmaxf(ly - dt, 0.f), hmax);
      y2 = fminf(fmaxf(ly + db, 0.f), hmax);
      vld = (x2 - x1 >= 0.f) && (y2 - y1 >= 0.f);
      sc = vld ? sqrtf((float)topval[tid]) : 0.f;
    } else { x1 = y1 = x2 = y2 = 0.f; lab = 1; vld = false; sc = 0.f; }
    ox1[tid] = x1; oy1[tid] = y1; ox2[tid] = x2; oy2[tid] = y2;
    osc[tid] = sc; olab[tid] = lab; oval[tid] = vld ? 1 : 0;
    float off = (float)lab * 1600.0f;   // max(size_h, size_w)
    float X1 = x1 + off, Y1 = y1 + off, X2 = x2 + off, Y2 = y2 + off;
    bx1[tid] = X1; by1[tid] = Y1; bx2[tid] = X2; by2[tid] = Y2;
    barea[tid] = fmaxf(X2 - X1, 0.f) * fmaxf(Y2 - Y1, 0.f);
  }
  __syncthreads();
  // greedy NMS on one wave: lane holds boxes j and j+64, keep masks in regs
  if (tid < 64) {
    const int lane = tid, j1 = lane + 64;
    float a_x1 = bx1[lane], a_y1 = by1[lane], a_x2 = bx2[lane], a_y2 = by2[lane], a_ar = barea[lane];
    float c_x1 = 0, c_y1 = 0, c_x2 = 0, c_y2 = 0, c_ar = 0;
    if (j1 < KTOP) { c_x1 = bx1[j1]; c_y1 = by1[j1]; c_x2 = bx2[j1]; c_y2 = by2[j1]; c_ar = barea[j1]; }
    unsigned long long k0 = 0ull, k1 = 0ull;
    for (int i = 0; i < KTOP; ++i) {
      float ix1 = bx1[i], iy1 = by1[i], ix2 = bx2[i], iy2 = by2[i], iar = barea[i];
      bool s0 = false, s1 = false;
      if (lane < i && ((k0 >> lane) & 1ull)) {
        float w = fmaxf(fminf(ix2, a_x2) - fmaxf(ix1, a_x1), 0.f);
        float h = fmaxf(fminf(iy2, a_y2) - fmaxf(iy1, a_y1), 0.f);
        float inter = w*h;
        s0 = inter / (iar + a_ar - inter + 1e-9f) > 0.6f;
      }
      if (j1 < i && ((k1 >> lane) & 1ull)) {
        float w = fmaxf(fminf(ix2, c_x2) - fmaxf(ix1, c_x1), 0.f);
        float h = fmaxf(fminf(iy2, c_y2) - fmaxf(iy1, c_y1), 0.f);
        float inter = w*h;
        s1 = inter / (iar + c_ar - inter + 1e-9f) > 0.6f;
      }
      unsigned long long b0 = __ballot(s0), b1 = __ballot(s1);
      bool keep_i = (oval[i] != 0) && ((b0 | b1) == 0ull);
      if (keep_i) { if (i < 64) k0 |= 1ull << i; else k1 |= 1ull << (i - 64); }
    }
    okeep[lane] = (unsigned char)((k0 >> lane) & 1ull);
    if (j1 < KTOP) okeep[j1] = (unsigned char)((k1 >> lane) & 1ull);
  }
  __syncthreads();
  if (tid < KTOP) {
    float* ob = out;                       // boxes  [16][100][4]
    float* os = out + NIMG*KTOP*4;         // scores [16][100]
    float* ol = os + NIMG*KTOP;            // labels [16][100]
    float* ok = ol + NIMG*KTOP;            // keep   [16][100]
    int base = n*KTOP + tid;
    ob[base*4 + 0] = ox1[tid]; ob[base*4 + 1] = oy1[tid];
    ob[base*4 + 2] = ox2[tid]; ob[base*4 + 3] = oy2[tid];
    bool kp = okeep[tid] != 0;
    os[base] = kp ? osc[tid] : 0.f;
    ol[base] = (float)olab[tid];
    ok[base] = kp ? 1.f : 0.f;
  }
}

extern "C" void kernel_launch(void* const* d_in, const int* in_sizes, int n_in,
                              void* d_out, int out_size, void* d_ws, size_t ws_size,
                              hipStream_t stream) {
  const float* locs = (const float*)d_in[0];   // [HW,2]
  const float* cls  = (const float*)d_in[1];   // [16,80,200,152]
  const float* reg  = (const float*)d_in[2];   // [16,4,200,152]
  const float* cent = (const float*)d_in[3];   // [16,1,200,152]
  char* ws = (char*)d_ws;
  int*   hist     = (int*)(ws + HIST_OFF);
  int*   cnt      = (int*)(ws + CNT_OFF);
  int*   tbin     = (int*)(ws + TBIN_OFF);
  int*   cand_idx = (int*)(ws + CIDX_OFF);
  float* cand_val = (float*)(ws + CVAL_OFF);
  float* out = (float*)d_out;

  hipMemsetAsync(d_ws, 0, ZERO_BYTES, stream);
  dim3 gridA(CHUNKS4, NIMG);
  k_hist_collect<<<gridA, 256, 0, stream>>>(cls, cent, hist, cnt, cand_idx, cand_val);
  k_thresh<<<NIMG, 256, 0, stream>>>(hist, tbin);
  dim3 gridF(CHUNKS, NIMG);
  k_collect_fb<<<gridF, 256, 0, stream>>>(cls, cent, tbin, cnt, cand_idx, cand_val);
  k_final<<<NIMG, 256, 0, stream>>>(cls, cent, reg, locs, tbin, cnt,
                                    cand_idx, cand_val, out);
}

// Round 3
// 314.763 us; speedup vs baseline: 1.0682x; 1.0682x over previous
//
#include <hip/hip_runtime.h>
#include <math.h>

#define NIMG 16
#define NC   80
#define HH   200
#define WW   152
#define HWSZ (HH*WW)          // 30400
#define HW4  (HWSZ/4)         // 7600
#define KTOP 100
#define NBINS 4096
#define CAP   16384           // per-image collected candidate capacity
#define SCAP  512             // per-block staging capacity (pass 1)
#define FCAP  1024            // finalist capacity (k_final)
#define CPG   16              // classes per block (pass 1)
#define CGRP  (NC/CPG)        // 5
#define CHUNKS4 30            // ceil(7600/256)

// ws layout (bytes):
//   cnt  [16] int            @ 0
//   tbin [16] int            @ 64
//   cand_idx [16][CAP] int   @ 128
//   cand_val [16][CAP] float @ 128 + 1 MiB
#define CNT_OFF  0
#define TBIN_OFF 64
#define CIDX_OFF 128
#define CVAL_OFF (128 + NIMG*CAP*4)
#define ZERO_BYTES 128

__device__ __forceinline__ float sigf(float x){ return 1.f/(1.f+expf(-x)); }

// Pass 1 (hot): collect all candidates with comb = sigmoid(cls)*sigmoid(cent) > 0.5.
// comb>0.5 implies s>0.5 (x>0), so the expf precheck is exact, and s>0.2 holds.
__global__ void __launch_bounds__(256) k_collect(
    const float* __restrict__ cls, const float* __restrict__ cent,
    int* __restrict__ cnt, int* __restrict__ cand_idx, float* __restrict__ cand_val)
{
  __shared__ int lcnt, gbase;
  __shared__ int   lidx[SCAP];
  __shared__ float lval[SCAP];
  const int n = blockIdx.y, g = blockIdx.z;
  const int idx4 = blockIdx.x*256 + threadIdx.x;
  if (threadIdx.x == 0) lcnt = 0;
  __syncthreads();
  if (idx4 < HW4) {
    const float4 ct4 = ((const float4*)cent)[n*HW4 + idx4];
    float cs[4];
    cs[0] = sigf(ct4.x); cs[1] = sigf(ct4.y); cs[2] = sigf(ct4.z); cs[3] = sigf(ct4.w);
    const float4* cp = (const float4*)(cls + (size_t)n*NC*HWSZ + (size_t)g*CPG*HWSZ) + idx4;
    const int hw0 = idx4*4;
    #pragma unroll 4
    for (int c = 0; c < CPG; ++c) {
      float4 v = cp[(size_t)c*HW4];
      float x[4] = {v.x, v.y, v.z, v.w};
      #pragma unroll
      for (int e = 0; e < 4; ++e) {
        if (x[e] > 0.f) {                    // s>0.5 necessary for comb>0.5
          float s = sigf(x[e]);
          float comb = s*cs[e];
          if (comb > 0.5f) {
            int gi = (hw0+e)*NC + (g*CPG + c);
            int p = atomicAdd(&lcnt, 1);
            if (p < SCAP) { lidx[p] = gi; lval[p] = comb; }
            else {                           // staging overflow (never in practice)
              int gg = atomicAdd(&cnt[n], 1);
              if (gg < CAP) { cand_idx[n*CAP+gg] = gi; cand_val[n*CAP+gg] = comb; }
            }
          }
        }
      }
    }
  }
  __syncthreads();
  int nc = lcnt; if (nc > SCAP) nc = SCAP;
  if (threadIdx.x == 0) gbase = atomicAdd(&cnt[n], nc);
  __syncthreads();
  for (int i = threadIdx.x; i < nc; i += 256) {
    int g2 = gbase + i;
    if (g2 < CAP) { cand_idx[n*CAP+g2] = lidx[i]; cand_val[n*CAP+g2] = lval[i]; }
  }
}

// Pass 2 (cold safety net, one block per image; early-exits when cnt>=100):
// full-image histogram -> threshold bin T -> collect bins [T, 2048).
__global__ void __launch_bounds__(256) k_fallback(
    const float* __restrict__ cls, const float* __restrict__ cent,
    int* __restrict__ cnt, int* __restrict__ tbin,
    int* __restrict__ cand_idx, float* __restrict__ cand_val)
{
  const int n = blockIdx.x, tid = threadIdx.x;
  if (cnt[n] >= KTOP) { if (tid == 0) tbin[n] = 2048; return; }
  __shared__ int lh[NBINS];
  __shared__ int sT;
  for (int b = tid; b < NBINS; b += 256) lh[b] = 0;
  __syncthreads();
  for (int hw = tid; hw < HWSZ; hw += 256) {
    float cs = sigf(cent[n*HWSZ + hw]);
    const float* cp = cls + (size_t)n*NC*HWSZ + hw;
    for (int c = 0; c < NC; ++c) {
      float s = sigf(cp[(size_t)c*HWSZ]);
      if (s > 0.2f) {
        float comb = s*cs;
        int b = (int)(comb*4096.f); if (b > 4095) b = 4095;
        atomicAdd(&lh[b], 1);
      }
    }
  }
  __syncthreads();
  if (tid == 0) {
    int run = 0, T = 0;
    for (int b = NBINS-1; b >= 0; --b) { run += lh[b]; if (run >= KTOP) { T = b; break; } }
    sT = T; tbin[n] = T;
  }
  __syncthreads();
  const int T = sT;
  for (int hw = tid; hw < HWSZ; hw += 256) {
    float cs = sigf(cent[n*HWSZ + hw]);
    const float* cp = cls + (size_t)n*NC*HWSZ + hw;
    for (int c = 0; c < NC; ++c) {
      float s = sigf(cp[(size_t)c*HWSZ]);
      if (s > 0.2f) {
        float comb = s*cs;
        if (!(comb > 0.5f)) {          // comb>0.5 already collected by pass 1
          int b = (int)(comb*4096.f);
          if (b >= T) {
            int g = atomicAdd(&cnt[n], 1);
            if (g < CAP) { cand_idx[n*CAP+g] = hw*NC + c; cand_val[n*CAP+g] = comb; }
          }
        }
      }
    }
  }
}

// Pass 3: per image — local 256-bin refine, exact top-100 (f64 rank), decode, NMS.
__global__ void __launch_bounds__(256) k_final(
    const float* __restrict__ cls, const float* __restrict__ cent,
    const float* __restrict__ reg, const float* __restrict__ locs,
    const int* __restrict__ tbin, const int* __restrict__ cnt,
    const int* __restrict__ cand_idx, const float* __restrict__ cand_val,
    float* __restrict__ out)
{
  const int n = blockIdx.x, tid = threadIdx.x;
  __shared__ int rh[256];
  __shared__ int sR, fcnt;
  __shared__ int    fidx[FCAP];
  __shared__ double fval[FCAP];
  __shared__ int    topidx[KTOP];
  __shared__ double topval[KTOP];
  __shared__ float bx1[KTOP], by1[KTOP], bx2[KTOP], by2[KTOP], barea[KTOP];
  __shared__ float ox1[KTOP], oy1[KTOP], ox2[KTOP], oy2[KTOP], osc[KTOP];
  __shared__ int olab[KTOP];
  __shared__ unsigned char oval[KTOP], okeep[KTOP];
  rh[tid] = 0;
  if (tid == 0) fcnt = 0;
  for (int k = tid; k < KTOP; k += 256) topidx[k] = -1;
  __syncthreads();
  const int T = tbin[n];
  const float lo = (float)T * (1.f/4096.f);
  const float scale = 256.f / (1.f - lo);
  int m = cnt[n]; if (m > CAP) m = CAP;
  // pass A: refine histogram over candidates with coarse bin >= T
  for (int i = tid; i < m; i += 256) {
    float v = cand_val[n*CAP + i];
    int b = (int)(v*4096.f); if (b > 4095) b = 4095;
    if (b >= T) {
      int r = (int)((v - lo)*scale); r = r < 0 ? 0 : (r > 255 ? 255 : r);
      atomicAdd(&rh[r], 1);
    }
  }
  __syncthreads();
  if (tid == 0) {
    int run = 0, R = 0;
    for (int r = 255; r >= 0; --r) { run += rh[r]; if (run >= KTOP) { R = r; break; } }
    sR = R;
  }
  __syncthreads();
  const int R = sR;
  // pass B: stage finalists (refined bin >= R)
  for (int i = tid; i < m; i += 256) {
    float v = cand_val[n*CAP + i];
    int b = (int)(v*4096.f); if (b > 4095) b = 4095;
    if (b >= T) {
      int r = (int)((v - lo)*scale); r = r < 0 ? 0 : (r > 255 ? 255 : r);
      if (r >= R) { int p = atomicAdd(&fcnt, 1); if (p < FCAP) fidx[p] = cand_idx[n*CAP + i]; }
    }
  }
  __syncthreads();
  int mf = fcnt; if (mf > FCAP) mf = FCAP;
  // f64 recompute of combined score for robust ordering
  for (int i = tid; i < mf; i += 256) {
    int idx = fidx[i]; int loc = idx / NC; int c = idx - loc*NC;
    double s  = 1.0/(1.0 + exp(-(double)cls[(size_t)n*NC*HWSZ + (size_t)c*HWSZ + loc]));
    double ct = 1.0/(1.0 + exp(-(double)cent[n*HWSZ + loc]));
    fval[i] = s*ct;
  }
  __syncthreads();
  // exact rank (desc value, asc index tie-break)
  for (int i = tid; i < mf; i += 256) {
    double vi = fval[i]; int ii = fidx[i]; int r = 0;
    for (int j = 0; j < mf; ++j) {
      double vj = fval[j];
      r += (vj > vi) || (vj == vi && fidx[j] < ii);
    }
    if (r < KTOP) { topidx[r] = ii; topval[r] = vi; }
  }
  __syncthreads();
  if (tid < KTOP) {
    int idx = topidx[tid];
    float x1, y1, x2, y2, sc; int lab; bool vld;
    if (idx >= 0) {
      int loc = idx / NC; int c = idx - loc*NC; lab = c + 1;
      float lx = locs[2*loc], ly = locs[2*loc + 1];
      const float* rp = reg + (size_t)n*4*HWSZ;
      float dl = rp[loc], dt = rp[HWSZ + loc], dr = rp[2*HWSZ + loc], db = rp[3*HWSZ + loc];
      const float wmax = (float)(WW*8 - 1);   // 1215
      const float hmax = (float)(HH*8 - 1);   // 1599
      x1 = fminf(fmaxf(lx - dl, 0.f), wmax);
      x2 = fminf(fmaxf(lx + dr, 0.f), wmax);
      y1 = fminf(fmaxf(ly - dt, 0.f), hmax);
      y2 = fminf(fmaxf(ly + db, 0.f), hmax);
      vld = (x2 - x1 >= 0.f) && (y2 - y1 >= 0.f);
      sc = vld ? sqrtf((float)topval[tid]) : 0.f;
    } else { x1 = y1 = x2 = y2 = 0.f; lab = 1; vld = false; sc = 0.f; }
    ox1[tid] = x1; oy1[tid] = y1; ox2[tid] = x2; oy2[tid] = y2;
    osc[tid] = sc; olab[tid] = lab; oval[tid] = vld ? 1 : 0;
    float off = (float)lab * 1600.0f;   // max(size_h, size_w)
    float X1 = x1 + off, Y1 = y1 + off, X2 = x2 + off, Y2 = y2 + off;
    bx1[tid] = X1; by1[tid] = Y1; bx2[tid] = X2; by2[tid] = Y2;
    barea[tid] = fmaxf(X2 - X1, 0.f) * fmaxf(Y2 - Y1, 0.f);
  }
  __syncthreads();
  // greedy NMS on one wave: lane holds boxes j and j+64, keep masks in regs
  if (tid < 64) {
    const int lane = tid, j1 = lane + 64;
    float a_x1 = bx1[lane], a_y1 = by1[lane], a_x2 = bx2[lane], a_y2 = by2[lane], a_ar = barea[lane];
    float c_x1 = 0, c_y1 = 0, c_x2 = 0, c_y2 = 0, c_ar = 0;
    if (j1 < KTOP) { c_x1 = bx1[j1]; c_y1 = by1[j1]; c_x2 = bx2[j1]; c_y2 = by2[j1]; c_ar = barea[j1]; }
    unsigned long long k0 = 0ull, k1 = 0ull;
    for (int i = 0; i < KTOP; ++i) {
      float ix1 = bx1[i], iy1 = by1[i], ix2 = bx2[i], iy2 = by2[i], iar = barea[i];
      bool s0 = false, s1 = false;
      if (lane < i && ((k0 >> lane) & 1ull)) {
        float w = fmaxf(fminf(ix2, a_x2) - fmaxf(ix1, a_x1), 0.f);
        float h = fmaxf(fminf(iy2, a_y2) - fmaxf(iy1, a_y1), 0.f);
        float inter = w*h;
        s0 = inter / (iar + a_ar - inter + 1e-9f) > 0.6f;
      }
      if (j1 < i && ((k1 >> lane) & 1ull)) {
        float w = fmaxf(fminf(ix2, c_x2) - fmaxf(ix1, c_x1), 0.f);
        float h = fmaxf(fminf(iy2, c_y2) - fmaxf(iy1, c_y1), 0.f);
        float inter = w*h;
        s1 = inter / (iar + c_ar - inter + 1e-9f) > 0.6f;
      }
      unsigned long long b0 = __ballot(s0), b1 = __ballot(s1);
      bool keep_i = (oval[i] != 0) && ((b0 | b1) == 0ull);
      if (keep_i) { if (i < 64) k0 |= 1ull << i; else k1 |= 1ull << (i - 64); }
    }
    okeep[lane] = (unsigned char)((k0 >> lane) & 1ull);
    if (j1 < KTOP) okeep[j1] = (unsigned char)((k1 >> lane) & 1ull);
  }
  __syncthreads();
  if (tid < KTOP) {
    float* ob = out;                       // boxes  [16][100][4]
    float* os = out + NIMG*KTOP*4;         // scores [16][100]
    float* ol = os + NIMG*KTOP;            // labels [16][100]
    float* ok = ol + NIMG*KTOP;            // keep   [16][100]
    int base = n*KTOP + tid;
    ob[base*4 + 0] = ox1[tid]; ob[base*4 + 1] = oy1[tid];
    ob[base*4 + 2] = ox2[tid]; ob[base*4 + 3] = oy2[tid];
    bool kp = okeep[tid] != 0;
    os[base] = kp ? osc[tid] : 0.f;
    ol[base] = (float)olab[tid];
    ok[base] = kp ? 1.f : 0.f;
  }
}

extern "C" void kernel_launch(void* const* d_in, const int* in_sizes, int n_in,
                              void* d_out, int out_size, void* d_ws, size_t ws_size,
                              hipStream_t stream) {
  const float* locs = (const float*)d_in[0];   // [HW,2]
  const float* cls  = (const float*)d_in[1];   // [16,80,200,152]
  const float* reg  = (const float*)d_in[2];   // [16,4,200,152]
  const float* cent = (const float*)d_in[3];   // [16,1,200,152]
  char* ws = (char*)d_ws;
  int*   cnt      = (int*)(ws + CNT_OFF);
  int*   tbin     = (int*)(ws + TBIN_OFF);
  int*   cand_idx = (int*)(ws + CIDX_OFF);
  float* cand_val = (float*)(ws + CVAL_OFF);
  float* out = (float*)d_out;

  hipMemsetAsync(d_ws, 0, ZERO_BYTES, stream);
  dim3 gridC(CHUNKS4, NIMG, CGRP);
  k_collect<<<gridC, 256, 0, stream>>>(cls, cent, cnt, cand_idx, cand_val);
  k_fallback<<<NIMG, 256, 0, stream>>>(cls, cent, cnt, tbin, cand_idx, cand_val);
  k_final<<<NIMG, 256, 0, stream>>>(cls, cent, reg, locs, tbin, cnt,
                                    cand_idx, cand_val, out);
}

// Round 4
// 311.243 us; speedup vs baseline: 1.0803x; 1.0113x over previous
//
#include <hip/hip_runtime.h>
#include <math.h>

#define NIMG 16
#define NC   80
#define HH   200
#define WW   152
#define HWSZ (HH*WW)          // 30400
#define HW4  (HWSZ/4)         // 7600
#define KTOP 100
#define NBINS 4096
#define CAP   16384           // per-image collected candidate capacity
#define SCAP  512             // per-block staging capacity (pass 1)
#define FCAP  1024            // finalist capacity (k_final)
#define CPG   16              // classes per tile
#define CGRP  (NC/CPG)        // 5
#define CHUNKS4 30            // ceil(7600/256)
#define TILES (CHUNKS4*NIMG*CGRP)   // 2400
#define GRIDX 2048            // 8 blocks/CU exactly; grid-stride over TILES

// ws layout (bytes):
//   cnt  [16] int            @ 0
//   cand_idx [16][CAP] int   @ 128
//   cand_val [16][CAP] float @ 128 + 1 MiB
#define CNT_OFF  0
#define CIDX_OFF 128
#define CVAL_OFF (128 + NIMG*CAP*4)
#define ZERO_BYTES 128

__device__ __forceinline__ float sigf(float x){ return 1.f/(1.f+expf(-x)); }

// Pass 1 (hot): collect all candidates with comb = sigmoid(cls)*sigmoid(cent) > 0.5.
// comb>0.5 implies s>0.5 (x>0) so the x>0 precheck is exact, and s>0.2 holds.
// Balanced: 2048 blocks grid-stride over 2400 tiles (no low-occupancy tail).
__global__ void __launch_bounds__(256) k_collect(
    const float* __restrict__ cls, const float* __restrict__ cent,
    int* __restrict__ cnt, int* __restrict__ cand_idx, float* __restrict__ cand_val)
{
  __shared__ int lcnt, gbase;
  __shared__ int   lidx[SCAP];
  __shared__ float lval[SCAP];
  for (int tile = blockIdx.x; tile < TILES; tile += GRIDX) {
    const int g     = tile / (CHUNKS4*NIMG);
    const int r     = tile - g*(CHUNKS4*NIMG);
    const int n     = r / CHUNKS4;
    const int chunk = r - n*CHUNKS4;
    const int idx4  = chunk*256 + threadIdx.x;
    if (threadIdx.x == 0) lcnt = 0;
    __syncthreads();
    if (idx4 < HW4) {
      const float4 ct4 = ((const float4*)cent)[n*HW4 + idx4];
      float cs[4];
      cs[0] = sigf(ct4.x); cs[1] = sigf(ct4.y); cs[2] = sigf(ct4.z); cs[3] = sigf(ct4.w);
      const float4* cp = (const float4*)(cls + (size_t)n*NC*HWSZ + (size_t)g*CPG*HWSZ) + idx4;
      const int hw0 = idx4*4;
      #pragma unroll 8
      for (int c = 0; c < CPG; ++c) {
        float4 v = cp[(size_t)c*HW4];
        float x[4] = {v.x, v.y, v.z, v.w};
        #pragma unroll
        for (int e = 0; e < 4; ++e) {
          if (x[e] > 0.f) {                    // s>0.5 necessary for comb>0.5
            float s = sigf(x[e]);
            float comb = s*cs[e];
            if (comb > 0.5f) {
              int gi = (hw0+e)*NC + (g*CPG + c);
              int p = atomicAdd(&lcnt, 1);
              if (p < SCAP) { lidx[p] = gi; lval[p] = comb; }
              else {                           // staging overflow (never in practice)
                int gg = atomicAdd(&cnt[n], 1);
                if (gg < CAP) { cand_idx[n*CAP+gg] = gi; cand_val[n*CAP+gg] = comb; }
              }
            }
          }
        }
      }
    }
    __syncthreads();
    int nc = lcnt; if (nc > SCAP) nc = SCAP;
    if (threadIdx.x == 0) gbase = atomicAdd(&cnt[n], nc);
    __syncthreads();
    for (int i = threadIdx.x; i < nc; i += 256) {
      int g2 = gbase + i;
      if (g2 < CAP) { cand_idx[n*CAP+g2] = lidx[i]; cand_val[n*CAP+g2] = lval[i]; }
    }
    __syncthreads();
  }
}

// Pass 2: per image — finalist selection (hot: 256-bin refine over collected
// candidates; cold safety net: full-image 4096-bin rescan), exact top-100
// (f64 rank), decode, clip, greedy NMS, write all outputs.
__global__ void __launch_bounds__(256) k_final(
    const float* __restrict__ cls, const float* __restrict__ cent,
    const float* __restrict__ reg, const float* __restrict__ locs,
    const int* __restrict__ cnt,
    const int* __restrict__ cand_idx, const float* __restrict__ cand_val,
    float* __restrict__ out)
{
  const int n = blockIdx.x, tid = threadIdx.x;
  __shared__ int lh[NBINS];          // cold-path histogram (16 KB; 16 blocks total)
  __shared__ int rh[256];
  __shared__ int sR, sT, fcnt;
  __shared__ int    fidx[FCAP];
  __shared__ double fval[FCAP];
  __shared__ int    topidx[KTOP];
  __shared__ double topval[KTOP];
  __shared__ float bx1[KTOP], by1[KTOP], bx2[KTOP], by2[KTOP], barea[KTOP];
  __shared__ float ox1[KTOP], oy1[KTOP], ox2[KTOP], oy2[KTOP], osc[KTOP];
  __shared__ int olab[KTOP];
  __shared__ unsigned char oval[KTOP], okeep[KTOP];

  rh[tid] = 0;
  if (tid == 0) fcnt = 0;
  for (int k = tid; k < KTOP; k += 256) topidx[k] = -1;
  __syncthreads();

  const int m0 = cnt[n];
  const bool bad = (m0 < KTOP) || (m0 > CAP);   // hot path provably complete otherwise
  if (!bad) {
    // All m0 collected candidates lie in (0.5, 1]; refine into 256 bins.
    for (int i = tid; i < m0; i += 256) {
      float v = cand_val[n*CAP + i];
      int r = (int)((v - 0.5f)*512.f); r = r < 0 ? 0 : (r > 255 ? 255 : r);
      atomicAdd(&rh[r], 1);
    }
    __syncthreads();
    if (tid == 0) {
      int run = 0, R = 0;
      for (int r = 255; r >= 0; --r) { run += rh[r]; if (run >= KTOP) { R = r; break; } }
      sR = R;
    }
    __syncthreads();
    const int R = sR;
    for (int i = tid; i < m0; i += 256) {
      float v = cand_val[n*CAP + i];
      int r = (int)((v - 0.5f)*512.f); r = r < 0 ? 0 : (r > 255 ? 255 : r);
      if (r >= R) { int p = atomicAdd(&fcnt, 1); if (p < FCAP) fidx[p] = cand_idx[n*CAP + i]; }
    }
  } else {
    // Cold safety net (never taken for this data): full-image scan.
    for (int b = tid; b < NBINS; b += 256) lh[b] = 0;
    __syncthreads();
    for (int hw = tid; hw < HWSZ; hw += 256) {
      float cs = sigf(cent[n*HWSZ + hw]);
      const float* cp = cls + (size_t)n*NC*HWSZ + hw;
      for (int c = 0; c < NC; ++c) {
        float s = sigf(cp[(size_t)c*HWSZ]);
        if (s > 0.2f) {
          float comb = s*cs;
          int b = (int)(comb*4096.f); if (b > 4095) b = 4095;
          atomicAdd(&lh[b], 1);
        }
      }
    }
    __syncthreads();
    if (tid == 0) {
      int run = 0, T = 0;
      for (int b = NBINS-1; b >= 0; --b) { run += lh[b]; if (run >= KTOP) { T = b; break; } }
      sT = T;
    }
    __syncthreads();
    const int T = sT;
    for (int hw = tid; hw < HWSZ; hw += 256) {
      float cs = sigf(cent[n*HWSZ + hw]);
      const float* cp = cls + (size_t)n*NC*HWSZ + hw;
      for (int c = 0; c < NC; ++c) {
        float s = sigf(cp[(size_t)c*HWSZ]);
        if (s > 0.2f) {
          float comb = s*cs;
          int b = (int)(comb*4096.f); if (b > 4095) b = 4095;
          if (b >= T) { int p = atomicAdd(&fcnt, 1); if (p < FCAP) fidx[p] = hw*NC + c; }
        }
      }
    }
  }
  __syncthreads();
  int mf = fcnt; if (mf > FCAP) mf = FCAP;
  // f64 recompute of combined score for robust ordering
  for (int i = tid; i < mf; i += 256) {
    int idx = fidx[i]; int loc = idx / NC; int c = idx - loc*NC;
    double s  = 1.0/(1.0 + exp(-(double)cls[(size_t)n*NC*HWSZ + (size_t)c*HWSZ + loc]));
    double ct = 1.0/(1.0 + exp(-(double)cent[n*HWSZ + loc]));
    fval[i] = s*ct;
  }
  __syncthreads();
  // exact rank (desc value, asc index tie-break)
  for (int i = tid; i < mf; i += 256) {
    double vi = fval[i]; int ii = fidx[i]; int r = 0;
    for (int j = 0; j < mf; ++j) {
      double vj = fval[j];
      r += (vj > vi) || (vj == vi && fidx[j] < ii);
    }
    if (r < KTOP) { topidx[r] = ii; topval[r] = vi; }
  }
  __syncthreads();
  if (tid < KTOP) {
    int idx = topidx[tid];
    float x1, y1, x2, y2, sc; int lab; bool vld;
    if (idx >= 0) {
      int loc = idx / NC; int c = idx - loc*NC; lab = c + 1;
      float lx = locs[2*loc], ly = locs[2*loc + 1];
      const float* rp = reg + (size_t)n*4*HWSZ;
      float dl = rp[loc], dt = rp[HWSZ + loc], dr = rp[2*HWSZ + loc], db = rp[3*HWSZ + loc];
      const float wmax = (float)(WW*8 - 1);   // 1215
      const float hmax = (float)(HH*8 - 1);   // 1599
      x1 = fminf(fmaxf(lx - dl, 0.f), wmax);
      x2 = fminf(fmaxf(lx + dr, 0.f), wmax);
      y1 = fminf(fmaxf(ly - dt, 0.f), hmax);
      y2 = fminf(fmaxf(ly + db, 0.f), hmax);
      vld = (x2 - x1 >= 0.f) && (y2 - y1 >= 0.f);
      sc = vld ? sqrtf((float)topval[tid]) : 0.f;
    } else { x1 = y1 = x2 = y2 = 0.f; lab = 1; vld = false; sc = 0.f; }
    ox1[tid] = x1; oy1[tid] = y1; ox2[tid] = x2; oy2[tid] = y2;
    osc[tid] = sc; olab[tid] = lab; oval[tid] = vld ? 1 : 0;
    float off = (float)lab * 1600.0f;   // max(size_h, size_w)
    float X1 = x1 + off, Y1 = y1 + off, X2 = x2 + off, Y2 = y2 + off;
    bx1[tid] = X1; by1[tid] = Y1; bx2[tid] = X2; by2[tid] = Y2;
    barea[tid] = fmaxf(X2 - X1, 0.f) * fmaxf(Y2 - Y1, 0.f);
  }
  __syncthreads();
  // greedy NMS on one wave: lane holds boxes j and j+64, keep masks in regs
  if (tid < 64) {
    const int lane = tid, j1 = lane + 64;
    float a_x1 = bx1[lane], a_y1 = by1[lane], a_x2 = bx2[lane], a_y2 = by2[lane], a_ar = barea[lane];
    float c_x1 = 0, c_y1 = 0, c_x2 = 0, c_y2 = 0, c_ar = 0;
    if (j1 < KTOP) { c_x1 = bx1[j1]; c_y1 = by1[j1]; c_x2 = bx2[j1]; c_y2 = by2[j1]; c_ar = barea[j1]; }
    unsigned long long k0 = 0ull, k1 = 0ull;
    for (int i = 0; i < KTOP; ++i) {
      float ix1 = bx1[i], iy1 = by1[i], ix2 = bx2[i], iy2 = by2[i], iar = barea[i];
      bool s0 = false, s1 = false;
      if (lane < i && ((k0 >> lane) & 1ull)) {
        float w = fmaxf(fminf(ix2, a_x2) - fmaxf(ix1, a_x1), 0.f);
        float h = fmaxf(fminf(iy2, a_y2) - fmaxf(iy1, a_y1), 0.f);
        float inter = w*h;
        s0 = inter / (iar + a_ar - inter + 1e-9f) > 0.6f;
      }
      if (j1 < i && ((k1 >> lane) & 1ull)) {
        float w = fmaxf(fminf(ix2, c_x2) - fmaxf(ix1, c_x1), 0.f);
        float h = fmaxf(fminf(iy2, c_y2) - fmaxf(iy1, c_y1), 0.f);
        float inter = w*h;
        s1 = inter / (iar + c_ar - inter + 1e-9f) > 0.6f;
      }
      unsigned long long b0 = __ballot(s0), b1 = __ballot(s1);
      bool keep_i = (oval[i] != 0) && ((b0 | b1) == 0ull);
      if (keep_i) { if (i < 64) k0 |= 1ull << i; else k1 |= 1ull << (i - 64); }
    }
    okeep[lane] = (unsigned char)((k0 >> lane) & 1ull);
    if (j1 < KTOP) okeep[j1] = (unsigned char)((k1 >> lane) & 1ull);
  }
  __syncthreads();
  if (tid < KTOP) {
    float* ob = out;                       // boxes  [16][100][4]
    float* os = out + NIMG*KTOP*4;         // scores [16][100]
    float* ol = os + NIMG*KTOP;            // labels [16][100]
    float* ok = ol + NIMG*KTOP;            // keep   [16][100]
    int base = n*KTOP + tid;
    ob[base*4 + 0] = ox1[tid]; ob[base*4 + 1] = oy1[tid];
    ob[base*4 + 2] = ox2[tid]; ob[base*4 + 3] = oy2[tid];
    bool kp = okeep[tid] != 0;
    os[base] = kp ? osc[tid] : 0.f;
    ol[base] = (float)olab[tid];
    ok[base] = kp ? 1.f : 0.f;
  }
}

extern "C" void kernel_launch(void* const* d_in, const int* in_sizes, int n_in,
                              void* d_out, int out_size, void* d_ws, size_t ws_size,
                              hipStream_t stream) {
  const float* locs = (const float*)d_in[0];   // [HW,2]
  const float* cls  = (const float*)d_in[1];   // [16,80,200,152]
  const float* reg  = (const float*)d_in[2];   // [16,4,200,152]
  const float* cent = (const float*)d_in[3];   // [16,1,200,152]
  char* ws = (char*)d_ws;
  int*   cnt      = (int*)(ws + CNT_OFF);
  int*   cand_idx = (int*)(ws + CIDX_OFF);
  float* cand_val = (float*)(ws + CVAL_OFF);
  float* out = (float*)d_out;

  hipMemsetAsync(d_ws, 0, ZERO_BYTES, stream);
  k_collect<<<GRIDX, 256, 0, stream>>>(cls, cent, cnt, cand_idx, cand_val);
  k_final<<<NIMG, 256, 0, stream>>>(cls, cent, reg, locs, cnt,
                                    cand_idx, cand_val, out);
}